// Round 5
// baseline (311.021 us; speedup 1.0000x reference)
//
#include <hip/hip_runtime.h>

// Problem constants (B=16, T=512, N=2048, U=64) — all inputs/outputs FP32.
#define N_DIM 2048
#define U_DIM 64
#define M_DIM 8192   // B*T
#define K_DIM 2048   // = N

typedef __bf16 bf16x8 __attribute__((ext_vector_type(8)));
typedef float  floatx4 __attribute__((ext_vector_type(4)));
typedef unsigned short ushort8 __attribute__((ext_vector_type(8)));

#define AS1 __attribute__((address_space(1)))
#define AS3 __attribute__((address_space(3)))

__device__ __forceinline__ unsigned short f_to_bf16_rne(float f) {
    unsigned int x;
    __builtin_memcpy(&x, &f, 4);
    x += 0x7fffu + ((x >> 16) & 1u);
    return (unsigned short)(x >> 16);
}

// ---------------------------------------------------------------------------
// Kernel 1: wbar[k] = mean_i W[i,k]  (fp32), bmean = mean(b)
// ---------------------------------------------------------------------------
__global__ __launch_bounds__(256) void prep_kernel(
    const float* __restrict__ W, const float* __restrict__ b,
    float* __restrict__ wbar, float* __restrict__ bmean) {
    int k = blockIdx.x * 256 + threadIdx.x;
    float s = 0.f;
#pragma unroll
    for (int i = 0; i < U_DIM; ++i) s += W[i * N_DIM + k];
    wbar[k] = s * (1.f / U_DIM);

    if (blockIdx.x == 0 && threadIdx.x < 64) {
        float v = b[threadIdx.x];
#pragma unroll
        for (int off = 32; off > 0; off >>= 1) v += __shfl_down(v, off);
        if (threadIdx.x == 0) bmean[0] = v * (1.f / U_DIM);
    }
}

// ---------------------------------------------------------------------------
// Kernel 2 (merged): blocks [0, 2048): weff[j,k] = bf16(Adj[j,k]*wbar[k])
//                    blocks [2048, 10240): xbf = bf16(x)
// ---------------------------------------------------------------------------
__global__ __launch_bounds__(256) void weff_convx_kernel(
    const float* __restrict__ Adj, const float* __restrict__ wbar,
    unsigned short* __restrict__ weff,
    const float* __restrict__ x, unsigned short* __restrict__ xbf) {
    if (blockIdx.x < 2048) {
        long long idx = ((long long)blockIdx.x * 256 + threadIdx.x) * 8;
        int k = (int)(idx & (N_DIM - 1));
        floatx4 a0 = *(const floatx4*)(Adj + idx);
        floatx4 a1 = *(const floatx4*)(Adj + idx + 4);
        floatx4 w0 = *(const floatx4*)(wbar + k);
        floatx4 w1 = *(const floatx4*)(wbar + k + 4);
        ushort8 ov;
#pragma unroll
        for (int j = 0; j < 4; ++j) {
            ov[j]     = f_to_bf16_rne(a0[j] * w0[j]);
            ov[j + 4] = f_to_bf16_rne(a1[j] * w1[j]);
        }
        *(ushort8*)(weff + idx) = ov;
    } else {
        long long idx = ((long long)(blockIdx.x - 2048) * 256 + threadIdx.x) * 8;
        floatx4 a0 = *(const floatx4*)(x + idx);
        floatx4 a1 = *(const floatx4*)(x + idx + 4);
        ushort8 ov;
#pragma unroll
        for (int j = 0; j < 4; ++j) {
            ov[j]     = f_to_bf16_rne(a0[j]);
            ov[j + 4] = f_to_bf16_rne(a1[j]);
        }
        *(ushort8*)(xbf + idx) = ov;
    }
}

// Fallback converter for chunked path (small ws)
__global__ __launch_bounds__(256) void convx_kernel(
    const float* __restrict__ x, unsigned short* __restrict__ xbf) {
    long long idx = ((long long)blockIdx.x * 256 + threadIdx.x) * 8;
    floatx4 a0 = *(const floatx4*)(x + idx);
    floatx4 a1 = *(const floatx4*)(x + idx + 4);
    ushort8 ov;
#pragma unroll
    for (int j = 0; j < 4; ++j) {
        ov[j]     = f_to_bf16_rne(a0[j]);
        ov[j + 4] = f_to_bf16_rne(a1[j]);
    }
    *(ushort8*)(xbf + idx) = ov;
}

// ---------------------------------------------------------------------------
// Kernel 3: C[m,j] = sum_k A[m,k]*Bt[j,k] + bmean   (bf16 in, fp32 acc/out)
//
// R5 structural change (schedule was invariant R0-R4 at 33% MfmaUtil):
//  - B (weff) NEVER touches LDS: per-wave register double-buffer loaded
//    straight from global. B-panel per XCD = 1 MB (nt=id&7) -> L2-resident;
//    loads issued one full K-tile ahead -> L2 latency hidden under MFMA.
//  - LDS holds only A: sA[2][128*64] = 32 KB -> BM=128, 4 waves/block,
//    512 blocks = 2 independent blocks/CU (two barrier domains; stalls of
//    one block covered by the other — m114 mechanism).
//  - Per CU-K-tile DS load: 192 -> 128 b128 instrs; DS writes halved.
//
// Per-wave tile: 128x64 (mi 0..7, ni 0..3), acc 8x4 floatx4 (128 AGPR).
// K-loop manually unrolled x2 so the B register dbuf uses static names
// (rule #20: no runtime-indexed register arrays).
//
// vmcnt discipline (audited): steady state outstanding at tile t =
// [A(t)4, B(t)8 | A(t+1)4, B(t+1)8] -> vmcnt(12) drains exactly {A(t),B(t)}.
// Prologue issue order B(0), A(0), A(1) matches. Last tile drains to 0.
// ---------------------------------------------------------------------------
#define BM 128
#define BN 256
#define BK 64
#define NT (K_DIM / BK)   // 32

__global__ __launch_bounds__(256, 2) void gemm_bt_kernel(
    const unsigned short* __restrict__ A,    // [M, K] bf16 bits (xbf)
    const unsigned short* __restrict__ Bt,   // [N, K] bf16 bits (weff)
    const float* __restrict__ bmeanp,
    float* __restrict__ C,                   // [M, N] fp32
    int mtiles) {
    __shared__ __align__(16) unsigned short sA[2][BM * BK];  // 2 x 16 KB

    const int id   = blockIdx.x;
    const int nt   = id & 7;        // n-tile == XCD (round-robin dispatch)
    const int mt   = id >> 3;
    const int tile_m = mt * BM;
    const int tile_n = nt * BN;

    const int tid  = threadIdx.x;
    const int w    = tid >> 6;      // wave 0..3
    const int lane = tid & 63;

    const float bmean = bmeanp[0];

    // --- A staging: 16 chunks of 8 rows x 128 B; wave w stages chunks
    // w*4..w*4+3. lane l -> row l>>3, LDS slot l&7; pre-swizzled global
    // chunk kc = (l&7)^(l>>3): LDS[r][slot] = G[r][slot ^ (r&7)].
    const int srow = lane >> 3;
    const int skc  = (lane & 7) ^ srow;
    const unsigned short* gA0 = A + (size_t)(tile_m + w * 32 + srow) * K_DIM + skc * 8;

    // --- A fragment read offsets. 16x16x32 frag: m=lane&15, k=(lane>>4)*8+j.
    const int fr = lane & 15;
    const int fq = lane >> 4;       // 0..3
    int aoff[2];
#pragma unroll
    for (int s = 0; s < 2; ++s)
        aoff[s] = fr * BK + (((s * 4 + fq) ^ (fr & 7)) * 8);

    // --- B direct-from-global addressing: lane reads row tile_n + w*64 +
    // ni*16 + fr, cols k0 + s*32 + fq*8 (16 B). Advanced += BK per K-tile.
    const unsigned short* pB[4];
#pragma unroll
    for (int ni = 0; ni < 4; ++ni)
        pB[ni] = Bt + (size_t)(tile_n + w * 64 + ni * 16 + fr) * K_DIM + fq * 8;

    floatx4 acc[8][4];
#pragma unroll
    for (int mi = 0; mi < 8; ++mi)
#pragma unroll
        for (int ni = 0; ni < 4; ++ni) acc[mi][ni] = (floatx4){0.f, 0.f, 0.f, 0.f};

    #define STAGE_A(p, kt)                                                        \
        do {                                                                      \
            const int ko_ = (kt) * BK;                                            \
            _Pragma("unroll")                                                     \
            for (int i_ = 0; i_ < 4; ++i_) {                                      \
                __builtin_amdgcn_global_load_lds(                                 \
                    (const AS1 void*)(gA0 + ko_ + (size_t)i_ * 8 * K_DIM),        \
                    (AS3 void*)(&sA[(p)][(w * 4 + i_) * 8 * BK]), 16, 0, 0);      \
            }                                                                     \
        } while (0)

    // pB currently at tile-t base when entering BODY(t). RB_NXT gets tile t+1.
    #define BODY(T, RB_CUR, RB_NXT)                                               \
        do {                                                                      \
            const int t_ = (T);                                                   \
            const int p_ = t_ & 1;                                                \
            if (t_ + 1 < NT) {                                                    \
                _Pragma("unroll")                                                 \
                for (int ni = 0; ni < 4; ++ni) {                                  \
                    _Pragma("unroll")                                             \
                    for (int s = 0; s < 2; ++s)                                   \
                        RB_NXT[ni][s] =                                           \
                            *(const bf16x8*)(pB[ni] + BK + s * 32);               \
                }                                                                 \
            }                                                                     \
            if (t_ == NT - 1) asm volatile("s_waitcnt vmcnt(0)" ::: "memory");    \
            else              asm volatile("s_waitcnt vmcnt(12)" ::: "memory");   \
            __builtin_amdgcn_s_barrier();  /* A(t) published */                   \
            _Pragma("unroll")                                                     \
            for (int s = 0; s < 2; ++s) {                                         \
                bf16x8 af[8];                                                     \
                _Pragma("unroll")                                                 \
                for (int mi = 0; mi < 8; ++mi)                                    \
                    af[mi] = *(const bf16x8*)&sA[p_][aoff[s] + mi * 16 * BK];     \
                asm volatile("s_waitcnt lgkmcnt(0)" ::: "memory");                \
                __builtin_amdgcn_sched_barrier(0);                                \
                __builtin_amdgcn_s_setprio(1);                                    \
                _Pragma("unroll")                                                 \
                for (int mi = 0; mi < 8; ++mi) {                                  \
                    _Pragma("unroll")                                             \
                    for (int ni = 0; ni < 4; ++ni)                                \
                        acc[mi][ni] = __builtin_amdgcn_mfma_f32_16x16x32_bf16(    \
                            af[mi], RB_CUR[ni][s], acc[mi][ni], 0, 0, 0);         \
                }                                                                 \
                __builtin_amdgcn_s_setprio(0);                                    \
            }                                                                     \
            __builtin_amdgcn_s_barrier();  /* A buf p_ free */                    \
            if (t_ + 2 < NT) STAGE_A(p_, t_ + 2);                                 \
            _Pragma("unroll")                                                     \
            for (int ni = 0; ni < 4; ++ni) pB[ni] += BK;                          \
        } while (0)

    // prologue: issue order B(0), A(0), A(1)  (matches vmcnt(12) accounting)
    bf16x8 rb0[4][2], rb1[4][2];
#pragma unroll
    for (int ni = 0; ni < 4; ++ni)
#pragma unroll
        for (int s = 0; s < 2; ++s)
            rb0[ni][s] = *(const bf16x8*)(pB[ni] + s * 32);
    STAGE_A(0, 0);
    STAGE_A(1, 1);

    for (int tt = 0; tt < NT; tt += 2) {
        BODY(tt,     rb0, rb1);
        BODY(tt + 1, rb1, rb0);
    }
    #undef BODY
    #undef STAGE_A

    // Epilogue. 16x16 C/D: col = lane&15, row = (lane>>4)*4 + reg  [m89/m91]
    const int crow = tile_m + fq * 4;
    const int ccol = tile_n + w * 64 + fr;
#pragma unroll
    for (int mi = 0; mi < 8; ++mi)
#pragma unroll
        for (int ni = 0; ni < 4; ++ni)
#pragma unroll
            for (int r = 0; r < 4; ++r) {
                int gm = crow + mi * 16 + r;
                int gn = ccol + ni * 16;
                C[(size_t)gm * N_DIM + gn] = acc[mi][ni][r] + bmean;
            }
    (void)mtiles;
}

// ---------------------------------------------------------------------------
extern "C" void kernel_launch(void* const* d_in, const int* in_sizes, int n_in,
                              void* d_out, int out_size, void* d_ws, size_t ws_size,
                              hipStream_t stream) {
    (void)in_sizes; (void)n_in; (void)out_size;
    const float* x   = (const float*)d_in[0];  // [16,512,2048]
    const float* Adj = (const float*)d_in[1];  // [2048,2048]
    const float* W   = (const float*)d_in[2];  // [64,2048]
    const float* b   = (const float*)d_in[3];  // [64]
    float* out = (float*)d_out;                // [16,512,2048] fp32

    // ws: wbar @0 (8 KB) | bmean @8192 | weff bf16 @16384 (8.39 MB) | xbf
    char* ws = (char*)d_ws;
    float* wbar  = (float*)ws;
    float* bmean = (float*)(ws + 8192);
    unsigned short* weff = (unsigned short*)(ws + 16384);
    const size_t weff_bytes = (size_t)N_DIM * N_DIM * 2;
    const size_t xbf_off = 16384 + weff_bytes;
    unsigned short* xbf = (unsigned short*)(ws + xbf_off);

    size_t avail = (ws_size > xbf_off) ? (ws_size - xbf_off) : 0;
    long long max_rows = (long long)(avail / ((size_t)K_DIM * 2)) / BM * BM;
    if (max_rows < BM) max_rows = BM;
    if (max_rows > M_DIM) max_rows = M_DIM;

    prep_kernel<<<N_DIM / 256, 256, 0, stream>>>(W, b, wbar, bmean);

    if (max_rows == M_DIM) {
        // full-size path: merged weff+convx, then B-in-L2 GEMM (2 blocks/CU)
        weff_convx_kernel<<<2048 + M_DIM, 256, 0, stream>>>(Adj, wbar, weff, x, xbf);
        gemm_bt_kernel<<<(M_DIM / BM) * (N_DIM / BN), 256, 0, stream>>>(
            xbf, weff, bmean, out, M_DIM / BM);
    } else {
        weff_convx_kernel<<<2048, 256, 0, stream>>>(Adj, wbar, weff, x, xbf);
        for (long long m0 = 0; m0 < M_DIM; m0 += max_rows) {
            long long rows = (M_DIM - m0 < max_rows) ? (M_DIM - m0) : max_rows;
            convx_kernel<<<(int)rows, 256, 0, stream>>>(x + m0 * K_DIM, xbf);
            gemm_bt_kernel<<<(int)(rows / BM) * (N_DIM / BN), 256, 0, stream>>>(
                xbf, weff, bmean, out + m0 * (size_t)N_DIM, (int)(rows / BM));
        }
    }
}

// Round 6
// 219.437 us; speedup vs baseline: 1.4174x; 1.4174x over previous
//
#include <hip/hip_runtime.h>

// Problem constants (B=16, T=512, N=2048, U=64) — all inputs/outputs FP32.
#define N_DIM 2048
#define U_DIM 64
#define M_DIM 8192   // B*T
#define K_DIM 2048   // = N

typedef __bf16 bf16x8 __attribute__((ext_vector_type(8)));
typedef float  floatx4 __attribute__((ext_vector_type(4)));
typedef float  floatx16 __attribute__((ext_vector_type(16)));
typedef unsigned short ushort8 __attribute__((ext_vector_type(8)));

#define AS1 __attribute__((address_space(1)))
#define AS3 __attribute__((address_space(3)))

__device__ __forceinline__ unsigned short f_to_bf16_rne(float f) {
    unsigned int x;
    __builtin_memcpy(&x, &f, 4);
    x += 0x7fffu + ((x >> 16) & 1u);
    return (unsigned short)(x >> 16);
}

// ---------------------------------------------------------------------------
// Kernel 1: wbar[k] = mean_i W[i,k]  (fp32), bmean = mean(b)
// ---------------------------------------------------------------------------
__global__ __launch_bounds__(256) void prep_kernel(
    const float* __restrict__ W, const float* __restrict__ b,
    float* __restrict__ wbar, float* __restrict__ bmean) {
    int k = blockIdx.x * 256 + threadIdx.x;
    float s = 0.f;
#pragma unroll
    for (int i = 0; i < U_DIM; ++i) s += W[i * N_DIM + k];
    wbar[k] = s * (1.f / U_DIM);

    if (blockIdx.x == 0 && threadIdx.x < 64) {
        float v = b[threadIdx.x];
#pragma unroll
        for (int off = 32; off > 0; off >>= 1) v += __shfl_down(v, off);
        if (threadIdx.x == 0) bmean[0] = v * (1.f / U_DIM);
    }
}

// ---------------------------------------------------------------------------
// Kernel 2 (merged): blocks [0, 2048): weff[j,k] = bf16(Adj[j,k]*wbar[k])
//                    blocks [2048, 10240): xbf = bf16(x)
// ---------------------------------------------------------------------------
__global__ __launch_bounds__(256) void weff_convx_kernel(
    const float* __restrict__ Adj, const float* __restrict__ wbar,
    unsigned short* __restrict__ weff,
    const float* __restrict__ x, unsigned short* __restrict__ xbf) {
    if (blockIdx.x < 2048) {
        long long idx = ((long long)blockIdx.x * 256 + threadIdx.x) * 8;
        int k = (int)(idx & (N_DIM - 1));
        floatx4 a0 = *(const floatx4*)(Adj + idx);
        floatx4 a1 = *(const floatx4*)(Adj + idx + 4);
        floatx4 w0 = *(const floatx4*)(wbar + k);
        floatx4 w1 = *(const floatx4*)(wbar + k + 4);
        ushort8 ov;
#pragma unroll
        for (int j = 0; j < 4; ++j) {
            ov[j]     = f_to_bf16_rne(a0[j] * w0[j]);
            ov[j + 4] = f_to_bf16_rne(a1[j] * w1[j]);
        }
        *(ushort8*)(weff + idx) = ov;
    } else {
        long long idx = ((long long)(blockIdx.x - 2048) * 256 + threadIdx.x) * 8;
        floatx4 a0 = *(const floatx4*)(x + idx);
        floatx4 a1 = *(const floatx4*)(x + idx + 4);
        ushort8 ov;
#pragma unroll
        for (int j = 0; j < 4; ++j) {
            ov[j]     = f_to_bf16_rne(a0[j]);
            ov[j + 4] = f_to_bf16_rne(a1[j]);
        }
        *(ushort8*)(xbf + idx) = ov;
    }
}

// Fallback converter for chunked path (small ws)
__global__ __launch_bounds__(256) void convx_kernel(
    const float* __restrict__ x, unsigned short* __restrict__ xbf) {
    long long idx = ((long long)blockIdx.x * 256 + threadIdx.x) * 8;
    floatx4 a0 = *(const floatx4*)(x + idx);
    floatx4 a1 = *(const floatx4*)(x + idx + 4);
    ushort8 ov;
#pragma unroll
    for (int j = 0; j < 4; ++j) {
        ov[j]     = f_to_bf16_rne(a0[j]);
        ov[j + 4] = f_to_bf16_rne(a1[j]);
    }
    *(ushort8*)(xbf + idx) = ov;
}

// ---------------------------------------------------------------------------
// Kernel 3: C[m,j] = sum_k A[m,k]*Bt[j,k] + bmean   (bf16 in, fp32 acc/out)
//
// R6: R3's proven skeleton (staging, swizzle, vmcnt(8) 2-deep pipeline,
// 4-cluster rotation) with the MFMA shape switched 16x16x32 -> 32x32x16:
//   - half the MFMA instructions per wave-K-tile (64 -> 32 at 8 cyc each),
//     15% higher measured matrix ceiling (2382 vs 2075 TF)
//   - identical LDS bytes: 24 ds_read_b128/wave/K-tile; same XOR swizzle
//     (slot = kc ^ (lane&7), kc = s*2 + (lane>>5) for K-step s of 4)
//   - acc: 8 frags of f32x16 = 128 regs (unchanged); operands rotate <=64.
//
// Per K-tile t (p=t&1), same cluster shape as R3:
//   vmcnt(8) [0 on last] ; B1
//   init: read b01[2][2] + a0[4]
//   c1: issue a1[4]+b23[2][2] ; 8 MFMA (s=0)
//   c2: issue a2[4]           ; 8 MFMA (s=1)
//   c3: issue a3[4]           ; 8 MFMA (s=2)
//   c4: lgkm0 ; B2 ; STAGE(t+2 -> p) ; 8 MFMA (s=3)
//
// XCD mapping: grid = mtiles*8, nt = id&7, mt = id>>3 (1 MB B-panel per XCD).
// ---------------------------------------------------------------------------
#define BM 256
#define BN 256
#define BK 64
#define NT (K_DIM / BK)   // 32

__global__ __launch_bounds__(512, 2) void gemm_bt_kernel(
    const unsigned short* __restrict__ A,    // [M, K] bf16 bits (xbf)
    const unsigned short* __restrict__ Bt,   // [N, K] bf16 bits (weff)
    const float* __restrict__ bmeanp,
    float* __restrict__ C,                   // [M, N] fp32
    int mtiles) {
    __shared__ __align__(16) unsigned short sA[2][BM * BK];  // 2 x 32 KB
    __shared__ __align__(16) unsigned short sB[2][BN * BK];  // 2 x 32 KB

    const int id   = blockIdx.x;
    const int nt   = id & 7;        // n-tile == XCD (round-robin dispatch)
    const int mt   = id >> 3;
    const int tile_m = mt * BM;
    const int tile_n = nt * BN;

    const int tid  = threadIdx.x;
    const int w    = tid >> 6;      // wave 0..7
    const int lane = tid & 63;
    const int wm   = w >> 2;        // 0..1  (M split)
    const int wn   = w & 3;         // 0..3  (N split)

    const float bmean = bmeanp[0];

    // --- staging (identical to R3): wave w stages A/B chunks [w*4, w*4+4).
    // chunk = 8 rows x 128 B. lane l -> row l>>3, LDS slot l&7; pre-swizzled
    // global chunk kc = (l&7)^(l>>3): LDS[r][slot] = G[r][slot ^ (r&7)].
    const int srow = lane >> 3;
    const int skc  = (lane & 7) ^ srow;
    const unsigned short* gA0 = A  + (size_t)(tile_m + w * 32 + srow) * K_DIM + skc * 8;
    const unsigned short* gB0 = Bt + (size_t)(tile_n + w * 32 + srow) * K_DIM + skc * 8;

    // --- 32x32x16 fragment addressing. A: row=lane&31, k=(lane>>5)*8+j;
    // K-step s (of 4) -> chunk kc = s*2 + (lane>>5); slot = kc ^ (row&7),
    // and row&7 == lane&7 for every fragment row (bases are multiples of 32).
    const int ln31 = lane & 31;
    const int hq   = lane >> 5;     // 0..1
    const int l7   = lane & 7;
    int abase[4], bbase[2], slotk[4];
#pragma unroll
    for (int mi = 0; mi < 4; ++mi) abase[mi] = (wm * 128 + mi * 32 + ln31) * BK;
#pragma unroll
    for (int ni = 0; ni < 2; ++ni) bbase[ni] = (wn * 64 + ni * 32 + ln31) * BK;
#pragma unroll
    for (int s = 0; s < 4; ++s)    slotk[s] = ((s * 2 + hq) ^ l7) * 8;

    floatx16 acc[4][2];
#pragma unroll
    for (int mi = 0; mi < 4; ++mi)
#pragma unroll
        for (int ni = 0; ni < 2; ++ni)
#pragma unroll
            for (int r = 0; r < 16; ++r) acc[mi][ni][r] = 0.f;

    #define STAGE(p, kt)                                                          \
        do {                                                                      \
            const int koff_ = (kt) * BK;                                          \
            _Pragma("unroll")                                                     \
            for (int i_ = 0; i_ < 4; ++i_) {                                      \
                __builtin_amdgcn_global_load_lds(                                 \
                    (const AS1 void*)(gA0 + koff_ + (size_t)i_ * 8 * K_DIM),      \
                    (AS3 void*)(&sA[(p)][(w * 4 + i_) * 8 * BK]), 16, 0, 0);      \
                __builtin_amdgcn_global_load_lds(                                 \
                    (const AS1 void*)(gB0 + koff_ + (size_t)i_ * 8 * K_DIM),      \
                    (AS3 void*)(&sB[(p)][(w * 4 + i_) * 8 * BK]), 16, 0, 0);      \
            }                                                                     \
        } while (0)

    // prologue: tiles 0 and 1 in flight (16 outstanding per wave)
    STAGE(0, 0);
    STAGE(1, 1);

    for (int t = 0; t < NT; ++t) {
        const int p = t & 1;

        // tile t's 8 loads (oldest 8 of <=16) landed; newer 8 stay in flight.
        if (t == NT - 1) asm volatile("s_waitcnt vmcnt(0)" ::: "memory");
        else             asm volatile("s_waitcnt vmcnt(8)" ::: "memory");
        __builtin_amdgcn_s_barrier();               // B1: tile t visible

        bf16x8 b01[2][2], b23[2][2], a0[4], a1[4], a2[4], a3[4];

        // init burst: B s=0,1 + A s=0 (the only exposed LDS latency per tile)
#pragma unroll
        for (int ni = 0; ni < 2; ++ni)
#pragma unroll
            for (int s = 0; s < 2; ++s)
                b01[ni][s] = *(const bf16x8*)&sB[p][bbase[ni] + slotk[s]];
#pragma unroll
        for (int mi = 0; mi < 4; ++mi)
            a0[mi] = *(const bf16x8*)&sA[p][abase[mi] + slotk[0]];
        __builtin_amdgcn_sched_barrier(0);

        // ---- cluster 1: prefetch a1 + b23; MFMA s=0
#pragma unroll
        for (int mi = 0; mi < 4; ++mi)
            a1[mi] = *(const bf16x8*)&sA[p][abase[mi] + slotk[1]];
#pragma unroll
        for (int ni = 0; ni < 2; ++ni)
#pragma unroll
            for (int s = 0; s < 2; ++s)
                b23[ni][s] = *(const bf16x8*)&sB[p][bbase[ni] + slotk[2 + s]];
        __builtin_amdgcn_sched_barrier(0);
        __builtin_amdgcn_s_setprio(1);
#pragma unroll
        for (int mi = 0; mi < 4; ++mi)
#pragma unroll
            for (int ni = 0; ni < 2; ++ni)
                acc[mi][ni] = __builtin_amdgcn_mfma_f32_32x32x16_bf16(
                    a0[mi], b01[ni][0], acc[mi][ni], 0, 0, 0);
        __builtin_amdgcn_s_setprio(0);

        // ---- cluster 2: prefetch a2; MFMA s=1
#pragma unroll
        for (int mi = 0; mi < 4; ++mi)
            a2[mi] = *(const bf16x8*)&sA[p][abase[mi] + slotk[2]];
        __builtin_amdgcn_sched_barrier(0);
        __builtin_amdgcn_s_setprio(1);
#pragma unroll
        for (int mi = 0; mi < 4; ++mi)
#pragma unroll
            for (int ni = 0; ni < 2; ++ni)
                acc[mi][ni] = __builtin_amdgcn_mfma_f32_32x32x16_bf16(
                    a1[mi], b01[ni][1], acc[mi][ni], 0, 0, 0);
        __builtin_amdgcn_s_setprio(0);

        // ---- cluster 3: prefetch a3; MFMA s=2
#pragma unroll
        for (int mi = 0; mi < 4; ++mi)
            a3[mi] = *(const bf16x8*)&sA[p][abase[mi] + slotk[3]];
        __builtin_amdgcn_sched_barrier(0);
        __builtin_amdgcn_s_setprio(1);
#pragma unroll
        for (int mi = 0; mi < 4; ++mi)
#pragma unroll
            for (int ni = 0; ni < 2; ++ni)
                acc[mi][ni] = __builtin_amdgcn_mfma_f32_32x32x16_bf16(
                    a2[mi], b23[ni][0], acc[mi][ni], 0, 0, 0);
        __builtin_amdgcn_s_setprio(0);

        // ---- cluster 4: drain my reads, free buf p, stage t+2, MFMA s=3
        asm volatile("s_waitcnt lgkmcnt(0)" ::: "memory");
        __builtin_amdgcn_sched_barrier(0);
        __builtin_amdgcn_s_barrier();               // B2: buf p free
        if (t + 2 < NT) STAGE(p, t + 2);
        __builtin_amdgcn_sched_barrier(0);
        __builtin_amdgcn_s_setprio(1);
#pragma unroll
        for (int mi = 0; mi < 4; ++mi)
#pragma unroll
            for (int ni = 0; ni < 2; ++ni)
                acc[mi][ni] = __builtin_amdgcn_mfma_f32_32x32x16_bf16(
                    a3[mi], b23[ni][1], acc[mi][ni], 0, 0, 0);
        __builtin_amdgcn_s_setprio(0);
    }
    #undef STAGE

    // Epilogue. 32x32 C/D: col = lane&31, row = (reg&3)+8*(reg>>2)+4*(lane>>5)
    // [m74/m101]
    const int crow = tile_m + wm * 128 + hq * 4;
    const int ccol = tile_n + wn * 64 + ln31;
#pragma unroll
    for (int mi = 0; mi < 4; ++mi)
#pragma unroll
        for (int ni = 0; ni < 2; ++ni)
#pragma unroll
            for (int r = 0; r < 16; ++r) {
                int gm = crow + mi * 32 + (r & 3) + 8 * (r >> 2);
                int gn = ccol + ni * 32;
                C[(size_t)gm * N_DIM + gn] = acc[mi][ni][r] + bmean;
            }
    (void)mtiles;
}

// ---------------------------------------------------------------------------
extern "C" void kernel_launch(void* const* d_in, const int* in_sizes, int n_in,
                              void* d_out, int out_size, void* d_ws, size_t ws_size,
                              hipStream_t stream) {
    (void)in_sizes; (void)n_in; (void)out_size;
    const float* x   = (const float*)d_in[0];  // [16,512,2048]
    const float* Adj = (const float*)d_in[1];  // [2048,2048]
    const float* W   = (const float*)d_in[2];  // [64,2048]
    const float* b   = (const float*)d_in[3];  // [64]
    float* out = (float*)d_out;                // [16,512,2048] fp32

    // ws: wbar @0 (8 KB) | bmean @8192 | weff bf16 @16384 (8.39 MB) | xbf
    char* ws = (char*)d_ws;
    float* wbar  = (float*)ws;
    float* bmean = (float*)(ws + 8192);
    unsigned short* weff = (unsigned short*)(ws + 16384);
    const size_t weff_bytes = (size_t)N_DIM * N_DIM * 2;
    const size_t xbf_off = 16384 + weff_bytes;
    unsigned short* xbf = (unsigned short*)(ws + xbf_off);

    size_t avail = (ws_size > xbf_off) ? (ws_size - xbf_off) : 0;
    long long max_rows = (long long)(avail / ((size_t)K_DIM * 2)) / BM * BM;
    if (max_rows < BM) max_rows = BM;
    if (max_rows > M_DIM) max_rows = M_DIM;

    prep_kernel<<<N_DIM / 256, 256, 0, stream>>>(W, b, wbar, bmean);

    if (max_rows == M_DIM) {
        // full-size path: merged weff+convx, then one 256^2 8-wave GEMM
        weff_convx_kernel<<<2048 + M_DIM, 256, 0, stream>>>(Adj, wbar, weff, x, xbf);
        gemm_bt_kernel<<<(M_DIM / BM) * (N_DIM / BN), 512, 0, stream>>>(
            xbf, weff, bmean, out, M_DIM / BM);
    } else {
        weff_convx_kernel<<<2048, 256, 0, stream>>>(Adj, wbar, weff, x, xbf);
        for (long long m0 = 0; m0 < M_DIM; m0 += max_rows) {
            long long rows = (M_DIM - m0 < max_rows) ? (M_DIM - m0) : max_rows;
            convx_kernel<<<(int)rows, 256, 0, stream>>>(x + m0 * K_DIM, xbf);
            gemm_bt_kernel<<<(int)(rows / BM) * (N_DIM / BN), 512, 0, stream>>>(
                xbf, weff, bmean, out + m0 * (size_t)N_DIM, (int)(rows / BM));
        }
    }
}